// Round 3
// baseline (1441.601 us; speedup 1.0000x reference)
//
#include <hip/hip_runtime.h>

// out[r,f] = bias[f] + sum_{i: rows[i]==r} value[i] * weight[cols[i], f]
// R1 showed scatter write-allocate (248 MB for 32 MB payload) + shfl-serial
// spmv dominate. R2: coarse buckets (<=196 rows, LDS-sized), chunk-staged
// binning for line-sized scatter runs, LDS-atomic accumulation, no row sort.
//
// ws: [0,2K) gcnt[512] | [4K,6.1K) bucketBase[513] | [8K,10K) cursor[512]
//     [64K, 64K+8*nnz) pairs (ulong: val<<32 | lrow<<16 | col)

#define NBMAX 512
#define BIN_T 512
#define PPT 8
#define CHUNK (BIN_T * PPT)   // 4096 pairs per bin block
#define ACC_PAD 65            // LDS acc row stride (floats), breaks bank alignment

__global__ void k_zero512(int* __restrict__ p) { p[threadIdx.x] = 0; }

// Global bucket histogram (LDS-privatized).
__global__ void k_ghist(const int* __restrict__ rows, int nnz, unsigned M, int S,
                        int* __restrict__ gcnt, int NB) {
    __shared__ int h[NBMAX];
    int t = threadIdx.x;
    for (int i = t; i < NBMAX; i += blockDim.x) h[i] = 0;
    __syncthreads();
    for (int i = blockIdx.x * blockDim.x + t; i < nnz; i += gridDim.x * blockDim.x) {
        unsigned r = (unsigned)rows[i];
        int b = (int)(((unsigned long long)r * M) >> S);
        atomicAdd(&h[b], 1);
    }
    __syncthreads();
    for (int i = t; i < NB; i += blockDim.x)
        if (h[i]) atomicAdd(&gcnt[i], h[i]);
}

// Single-block scan: bucketBase (exclusive, +total at [NB]) and cursor init.
__global__ void k_gscan(const int* __restrict__ gcnt, int* __restrict__ bucketBase,
                        int* __restrict__ cursor, int NB) {
    __shared__ int s[NBMAX];
    int t = threadIdx.x;
    int v = (t < NB) ? gcnt[t] : 0;
    s[t] = v;
    __syncthreads();
    for (int off = 1; off < NBMAX; off <<= 1) {
        int x = (t >= off) ? s[t - off] : 0;
        __syncthreads();
        s[t] += x;
        __syncthreads();
    }
    int incl = s[t];
    if (t < NB) {
        cursor[t] = incl - v;
        if (t == 0) bucketBase[0] = 0;
        bucketBase[t + 1] = incl;
    }
}

// Bin pairs into bucket order. Chunk staged+sorted in LDS so global writes are
// contiguous runs per bucket (line-sized instead of 8 B random).
__global__ void k_bin(const int* __restrict__ rows, const int* __restrict__ cols,
                      const float* __restrict__ vals, int nnz, unsigned M, int S, int d,
                      int* __restrict__ cursor, unsigned long long* __restrict__ pairs) {
    __shared__ int hist[NBMAX];
    __shared__ int sc[NBMAX];
    __shared__ int sAdj[NBMAX];
    __shared__ unsigned long long stage[CHUNK];
    __shared__ unsigned short sbk[CHUNK];
    int t = threadIdx.x;
    long long base = (long long)blockIdx.x * CHUNK;
    int count = (int)min((long long)CHUNK, (long long)nnz - base);

    for (int i = t; i < NBMAX; i += BIN_T) hist[i] = 0;
    __syncthreads();

    int bb[PPT], rk[PPT];
    unsigned long long pk[PPT];
#pragma unroll
    for (int k = 0; k < PPT; ++k) {
        int i = t + k * BIN_T;
        bb[k] = -1;
        if (i < count) {
            unsigned r = (unsigned)rows[base + i];
            int c = cols[base + i];
            float v = vals[base + i];
            int b = (int)(((unsigned long long)r * M) >> S);
            int lr = (int)r - b * d;
            bb[k] = b;
            rk[k] = atomicAdd(&hist[b], 1);
            pk[k] = ((unsigned long long)__float_as_uint(v) << 32) |
                    ((unsigned)lr << 16) | (unsigned)c;
        }
    }
    __syncthreads();

    int v = hist[t];
    sc[t] = v;
    __syncthreads();
    for (int off = 1; off < NBMAX; off <<= 1) {
        int x = (t >= off) ? sc[t - off] : 0;
        __syncthreads();
        sc[t] += x;
        __syncthreads();
    }
    int excl = sc[t] - v;
    if (v > 0) {
        int g = atomicAdd(&cursor[t], v);
        sAdj[t] = g - excl;  // dest = sAdj[bucket] + stagePos
    }
    __syncthreads();

#pragma unroll
    for (int k = 0; k < PPT; ++k) {
        if (bb[k] >= 0) {
            int pos = (sc[bb[k]] - hist[bb[k]]) + rk[k];
            stage[pos] = pk[k];
            sbk[pos] = (unsigned short)bb[k];
        }
    }
    __syncthreads();

    for (int sIdx = t; sIdx < count; sIdx += BIN_T) {
        int b = sbk[sIdx];
        pairs[sAdj[b] + sIdx] = stage[sIdx];
    }
}

// One block per bucket: LDS fp32 accumulators (d rows x 64 feats), wave does
// 4 pairs/step: 16 lanes x float4 features. Single coalesced bias-fused store.
__global__ void k_spmm(const unsigned long long* __restrict__ pairs,
                       const int* __restrict__ bucketBase,
                       const float* __restrict__ weight, const float* __restrict__ bias,
                       float* __restrict__ out, int d, int n) {
    extern __shared__ float acc[];  // d * ACC_PAD floats
    int b = blockIdx.x;
    int t = threadIdx.x;
    int start = bucketBase[b], end = bucketBase[b + 1];
    int row0 = b * d;
    int nrows = min(d, n - row0);

    for (int i = t; i < d * ACC_PAD; i += blockDim.x) acc[i] = 0.0f;
    __syncthreads();

    int wave = t >> 6, lane = t & 63, nw = blockDim.x >> 6;
    int j4 = lane >> 4, fq = lane & 15;
#pragma unroll 2
    for (int p0 = start + wave * 4; p0 < end; p0 += nw * 4) {
        int idx = p0 + j4;
        if (idx < end) {
            unsigned long long p = pairs[idx];  // 16 lanes broadcast-load same addr
            int c = (int)(p & 0xffff);
            int lr = (int)((p >> 16) & 0xffff);
            float v = __uint_as_float((unsigned)(p >> 32));
            const float4 w = *(const float4*)(weight + (c << 6) + (fq << 2));
            float* a = &acc[lr * ACC_PAD + (fq << 2)];
            atomicAdd(a + 0, v * w.x);
            atomicAdd(a + 1, v * w.y);
            atomicAdd(a + 2, v * w.z);
            atomicAdd(a + 3, v * w.w);
        }
    }
    __syncthreads();

    for (int i = t; i < nrows * 64; i += blockDim.x) {
        int lr = i >> 6, f = i & 63;
        out[(long long)(row0 + lr) * 64 + f] = acc[lr * ACC_PAD + f] + bias[f];
    }
}

extern "C" void kernel_launch(void* const* d_in, const int* in_sizes, int n_in,
                              void* d_out, int out_size, void* d_ws, size_t ws_size,
                              hipStream_t stream) {
    const int*   index  = (const int*)d_in[0];
    const float* value  = (const float*)d_in[1];
    const float* weight = (const float*)d_in[3];
    const float* bias   = (const float*)d_in[4];
    float*       out    = (float*)d_out;

    int nnz = in_sizes[0] / 2;
    int n   = out_size / 64;
    const int* rows = index;
    const int* cols = index + nnz;

    // Bucketing: d rows per bucket, NB <= 512 buckets; exact div via magic mul.
    int d  = (n + NBMAX - 1) / NBMAX;      // 196 for n=100000
    int NB = (n + d - 1) / d;              // 511
    unsigned M = 0;
    int S = 0;
    for (S = 20; S <= 40; ++S) {
        unsigned long long m = ((1ull << S) + (unsigned)d - 1) / (unsigned)d;
        unsigned long long e = m * (unsigned long long)d - (1ull << S);
        if (m <= 0xffffffffull && e * (unsigned long long)(n > 0 ? n - 1 : 0) < (1ull << S)) {
            M = (unsigned)m;
            break;
        }
    }

    char* ws = (char*)d_ws;
    int* gcnt       = (int*)ws;                       // 512 ints
    int* bucketBase = (int*)(ws + 4096);              // 513 ints
    int* cursor     = (int*)(ws + 8192);              // 512 ints
    unsigned long long* pairs = (unsigned long long*)(ws + (64 << 10));  // nnz

    k_zero512<<<1, 512, 0, stream>>>(gcnt);
    k_ghist<<<256, 512, 0, stream>>>(rows, nnz, M, S, gcnt, NB);
    k_gscan<<<1, 512, 0, stream>>>(gcnt, bucketBase, cursor, NB);
    int binBlocks = (nnz + CHUNK - 1) / CHUNK;
    k_bin<<<binBlocks, BIN_T, 0, stream>>>(rows, cols, value, nnz, M, S, d, cursor, pairs);
    size_t smem = (size_t)d * ACC_PAD * sizeof(float);  // 196*65*4 = 50960 B
    k_spmm<<<NB, 512, smem, stream>>>(pairs, bucketBase, weight, bias, out, d, n);
}

// Round 4
// 235.717 us; speedup vs baseline: 6.1158x; 6.1158x over previous
//
#include <hip/hip_runtime.h>

// out[r,f] = bias[f] + sum_{i: rows[i]==r} value[i] * weight[cols[i], f]
// R2 post-mortem: k_bin (bucket binning, int LDS atomics) fine; k_spmm with
// ds_add_f32 per-pair LDS atomics catastrophic (1313 us, all pipes idle).
// R3: buckets of d=98 rows (NB=1021). Consumer sorts each chunk by local row
// in LDS (int-atomic rank, same pattern as k_bin), then waves process whole
// rows with plain register FMA — zero float atomics anywhere.
//
// ws: [0,4K) gcnt[1024] | [8K,12.1K) bucketBase[1025] | [16K,20K) cursor[1024]
//     [64K, 64K+8*nnz) pairs (u64: val<<32 | lrow<<16 | col)

#define NBMAX 1024
#define BIN_T 1024
#define BIN_PPT 4
#define CHUNK 4096
#define SP_T 512
#define SP_PPT 8     // CHUNK / SP_T
#define DCAP 98      // rows per bucket (n=100000 / 1024 buckets, ceil)

__global__ void k_zero1024(int* __restrict__ p) { p[threadIdx.x] = 0; }

__global__ void k_ghist(const int* __restrict__ rows, int nnz, unsigned M, int S,
                        int* __restrict__ gcnt, int NB) {
    __shared__ int h[NBMAX];
    int t = threadIdx.x;
    for (int i = t; i < NBMAX; i += blockDim.x) h[i] = 0;
    __syncthreads();
    for (int i = blockIdx.x * blockDim.x + t; i < nnz; i += gridDim.x * blockDim.x) {
        unsigned r = (unsigned)rows[i];
        int b = (int)(((unsigned long long)r * M) >> S);
        atomicAdd(&h[b], 1);
    }
    __syncthreads();
    for (int i = t; i < NB; i += blockDim.x)
        if (h[i]) atomicAdd(&gcnt[i], h[i]);
}

// Single block, 1024 threads: exclusive bases + cursor init.
__global__ void k_gscan(const int* __restrict__ gcnt, int* __restrict__ bucketBase,
                        int* __restrict__ cursor, int NB) {
    __shared__ int s[NBMAX];
    int t = threadIdx.x;
    int v = (t < NB) ? gcnt[t] : 0;
    s[t] = v;
    __syncthreads();
    for (int off = 1; off < NBMAX; off <<= 1) {
        int x = (t >= off) ? s[t - off] : 0;
        __syncthreads();
        s[t] += x;
        __syncthreads();
    }
    int incl = s[t];
    if (t < NB) {
        cursor[t] = incl - v;
        if (t == 0) bucketBase[0] = 0;
        bucketBase[t + 1] = incl;
    }
}

// Bin pairs into bucket order; chunk staged+sorted in LDS so global writes
// are contiguous runs per bucket.
__global__ void k_bin(const int* __restrict__ rows, const int* __restrict__ cols,
                      const float* __restrict__ vals, int nnz, unsigned M, int S, int d,
                      int* __restrict__ cursor, unsigned long long* __restrict__ pairs) {
    __shared__ int hist[NBMAX];
    __shared__ int sc[NBMAX];
    __shared__ int sAdj[NBMAX];
    __shared__ unsigned long long stage[CHUNK];
    __shared__ unsigned short sbk[CHUNK];
    int t = threadIdx.x;
    long long base = (long long)blockIdx.x * CHUNK;
    int count = (int)min((long long)CHUNK, (long long)nnz - base);

    hist[t] = 0;
    __syncthreads();

    int bb[BIN_PPT], rk[BIN_PPT];
    unsigned long long pk[BIN_PPT];
#pragma unroll
    for (int k = 0; k < BIN_PPT; ++k) {
        int i = t + k * BIN_T;
        bb[k] = -1;
        if (i < count) {
            unsigned r = (unsigned)rows[base + i];
            int c = cols[base + i];
            float v = vals[base + i];
            int b = (int)(((unsigned long long)r * M) >> S);
            int lr = (int)r - b * d;
            bb[k] = b;
            rk[k] = atomicAdd(&hist[b], 1);
            pk[k] = ((unsigned long long)__float_as_uint(v) << 32) |
                    ((unsigned)lr << 16) | (unsigned)c;
        }
    }
    __syncthreads();

    int v = hist[t];
    sc[t] = v;
    __syncthreads();
    for (int off = 1; off < NBMAX; off <<= 1) {
        int x = (t >= off) ? sc[t - off] : 0;
        __syncthreads();
        sc[t] += x;
        __syncthreads();
    }
    int excl = sc[t] - v;
    if (v > 0) {
        int g = atomicAdd(&cursor[t], v);
        sAdj[t] = g - excl;
    }
    __syncthreads();

#pragma unroll
    for (int k = 0; k < BIN_PPT; ++k) {
        if (bb[k] >= 0) {
            int pos = (sc[bb[k]] - hist[bb[k]]) + rk[k];
            stage[pos] = pk[k];
            sbk[pos] = (unsigned short)bb[k];
        }
    }
    __syncthreads();

    for (int sIdx = t; sIdx < count; sIdx += BIN_T) {
        int b = sbk[sIdx];
        pairs[sAdj[b] + sIdx] = stage[sIdx];
    }
}

// One block per bucket. Per chunk: rank pairs by local row (int LDS atomics),
// scatter into sorted stage, then wave w processes rows w, w+8, ... with
// register accumulation (lane = feature). No float atomics.
__global__ __launch_bounds__(SP_T) void k_spmm2(
        const unsigned long long* __restrict__ pairs, const int* __restrict__ bucketBase,
        const float* __restrict__ weight, const float* __restrict__ bias,
        float* __restrict__ out, int d, int n) {
    __shared__ unsigned long long stage[CHUNK];  // 32 KB
    __shared__ float acc[DCAP * 64];             // 25088 B
    __shared__ int hist[SP_T];                   // 2 KB
    __shared__ int sc[SP_T];                     // 2 KB

    int b = blockIdx.x;
    int t = threadIdx.x;
    int start = bucketBase[b], end = bucketBase[b + 1];
    int row0 = b * d;
    int nrows = min(d, n - row0);
    int wv = t >> 6, lane = t & 63, nw = SP_T >> 6;

    for (int i = t; i < DCAP * 64; i += SP_T) acc[i] = 0.0f;

    for (int cb = start; cb < end; cb += CHUNK) {
        int cnt = min(CHUNK, end - cb);
        hist[t] = 0;
        __syncthreads();

        unsigned long long pk[SP_PPT];
        int lr8[SP_PPT], rk8[SP_PPT];
#pragma unroll
        for (int k = 0; k < SP_PPT; ++k) {
            int i = t + k * SP_T;
            lr8[k] = -1;
            if (i < cnt) {
                unsigned long long p = pairs[cb + i];
                int lr = (int)((p >> 16) & 0xffff);
                lr8[k] = lr;
                rk8[k] = atomicAdd(&hist[lr], 1);
                pk[k] = p;
            }
        }
        __syncthreads();

        int v = hist[t];
        sc[t] = v;
        __syncthreads();
        for (int off = 1; off < SP_T; off <<= 1) {
            int x = (t >= off) ? sc[t - off] : 0;
            __syncthreads();
            sc[t] += x;
            __syncthreads();
        }

#pragma unroll
        for (int k = 0; k < SP_PPT; ++k) {
            if (lr8[k] >= 0) {
                int pos = (sc[lr8[k]] - hist[lr8[k]]) + rk8[k];
                stage[pos] = pk[k];
            }
        }
        __syncthreads();

        // Row phase: wave-exclusive rows, register accumulate, LDS RMW (plain).
        for (int lr = wv; lr < nrows; lr += nw) {
            int e = sc[lr];
            int s = e - hist[lr];
            if (s == e) continue;
            float a = 0.0f;
#pragma unroll 4
            for (int j = s; j < e; ++j) {
                unsigned long long p = stage[j];      // wave-uniform -> broadcast
                int c = (int)(p & 0xffff);
                float vv = __uint_as_float((unsigned)(p >> 32));
                a = fmaf(vv, weight[(c << 6) + lane], a);
            }
            acc[(lr << 6) + lane] += a;
        }
        __syncthreads();
    }

    float bf = bias[lane];
    for (int i = t; i < nrows * 64; i += SP_T)
        out[(long long)row0 * 64 + i] = acc[i] + bf;
}

extern "C" void kernel_launch(void* const* d_in, const int* in_sizes, int n_in,
                              void* d_out, int out_size, void* d_ws, size_t ws_size,
                              hipStream_t stream) {
    const int*   index  = (const int*)d_in[0];
    const float* value  = (const float*)d_in[1];
    const float* weight = (const float*)d_in[3];
    const float* bias   = (const float*)d_in[4];
    float*       out    = (float*)d_out;

    int nnz = in_sizes[0] / 2;
    int n   = out_size / 64;
    const int* rows = index;
    const int* cols = index + nnz;

    int d  = (n + NBMAX - 1) / NBMAX;   // 98 for n=100000 (== DCAP)
    int NB = (n + d - 1) / d;           // 1021
    unsigned M = 0;
    int S = 0;
    for (S = 20; S <= 40; ++S) {
        unsigned long long m = ((1ull << S) + (unsigned)d - 1) / (unsigned)d;
        unsigned long long e = m * (unsigned long long)d - (1ull << S);
        if (m <= 0xffffffffull && e * (unsigned long long)(n > 0 ? n - 1 : 0) < (1ull << S)) {
            M = (unsigned)m;
            break;
        }
    }

    char* ws = (char*)d_ws;
    int* gcnt       = (int*)ws;              // 1024 ints
    int* bucketBase = (int*)(ws + 8192);     // 1025 ints
    int* cursor     = (int*)(ws + 16384);    // 1024 ints
    unsigned long long* pairs = (unsigned long long*)(ws + (64 << 10));

    k_zero1024<<<1, 1024, 0, stream>>>(gcnt);
    k_ghist<<<256, 512, 0, stream>>>(rows, nnz, M, S, gcnt, NB);
    k_gscan<<<1, 1024, 0, stream>>>(gcnt, bucketBase, cursor, NB);
    int binBlocks = (nnz + CHUNK - 1) / CHUNK;
    k_bin<<<binBlocks, BIN_T, 0, stream>>>(rows, cols, value, nnz, M, S, d, cursor, pairs);
    k_spmm2<<<NB, SP_T, 0, stream>>>(pairs, bucketBase, weight, bias, out, d, n);
}

// Round 5
// 220.617 us; speedup vs baseline: 6.5344x; 1.0684x over previous
//
#include <hip/hip_runtime.h>

// out[r,f] = bias[f] + sum_{i: rows[i]==r} value[i] * weight[cols[i], f]
// R4 post-mortem: consumer row phase = 1 pair/wave-step, latency-bound (118us);
// k_bin writes 1M scattered 32B runs (write-allocate, ~95us). R5: two-level
// binning (64 coarse -> 1024 fine, runs 512B/2KB, single-writer lines) and a
// consumer with 4 rows in flight per wave (16 lanes x float4 each).
//
// pair pack (u64): val[63:32] | fine[29:20] | lr[19:13] | col[12:0]
// ws: gcnt@0 | fineBase@8K | cursorF@16K | cursorC@20K | pairs1@64K | pairs2 after

#define NBF 1024
#define DMAX 128     // lr fits 7 bits => d <= 128 (n <= 131072)
#define C1 4096
#define C2 4096
#define CC 2048

__global__ void k_zero1024(int* __restrict__ p) { p[threadIdx.x] = 0; }

__global__ void k_ghist(const int* __restrict__ rows, int nnz, unsigned M, int S,
                        int* __restrict__ gcnt) {
    __shared__ int h[NBF];
    int t = threadIdx.x;
    for (int i = t; i < NBF; i += blockDim.x) h[i] = 0;
    __syncthreads();
    for (int i = blockIdx.x * blockDim.x + t; i < nnz; i += gridDim.x * blockDim.x) {
        unsigned r = (unsigned)rows[i];
        int f = (int)(((unsigned long long)r * M) >> S);
        atomicAdd(&h[f], 1);
    }
    __syncthreads();
    for (int i = t; i < NBF; i += blockDim.x)
        if (h[i]) atomicAdd(&gcnt[i], h[i]);
}

// Single block, 1024 threads: fineBase (exclusive, +total), cursorF, cursorC.
__global__ __launch_bounds__(1024) void k_gscan(const int* __restrict__ gcnt,
        int* __restrict__ fineBase, int* __restrict__ cursorF, int* __restrict__ cursorC) {
    __shared__ int wsum[16];
    int t = threadIdx.x, lane = t & 63, wv = t >> 6;
    int v = gcnt[t];
    int x = v;
#pragma unroll
    for (int off = 1; off < 64; off <<= 1) {
        int y = __shfl_up(x, off, 64);
        if (lane >= off) x += y;
    }
    if (lane == 63) wsum[wv] = x;
    __syncthreads();
    if (t < 16) {
        int s = wsum[t], xs = s;
#pragma unroll
        for (int off = 1; off < 16; off <<= 1) {
            int y = __shfl_up(xs, off, 16);
            if (t >= off) xs += y;
        }
        wsum[t] = xs - s;
    }
    __syncthreads();
    int incl = x + wsum[wv];
    int excl = incl - v;
    fineBase[t] = excl;
    cursorF[t] = excl;
    if (t == NBF - 1) fineBase[NBF] = incl;
    if ((t & 15) == 0) cursorC[t >> 4] = excl;
}

// Pass 1: bin source triples to 64 coarse buckets (runs ~512 B, line-clean).
__global__ __launch_bounds__(512) void k_bin1(const int* __restrict__ rows,
        const int* __restrict__ cols, const float* __restrict__ vals, int nnz,
        unsigned M, int S, int d, int* __restrict__ cursorC,
        unsigned long long* __restrict__ pairs1) {
    __shared__ unsigned long long stage[C1];  // 32 KB
    __shared__ int histC[64], scC[64], adjC[64];
    int t = threadIdx.x;
    long long base = (long long)blockIdx.x * C1;
    int count = (int)min((long long)C1, (long long)nnz - base);
    if (t < 64) histC[t] = 0;
    __syncthreads();
    int cs8[8], rk8[8];
    unsigned long long pk8[8];
#pragma unroll
    for (int k = 0; k < 8; ++k) {
        int i = t + (k << 9);
        cs8[k] = -1;
        if (i < count) {
            unsigned r = (unsigned)rows[base + i];
            int c = cols[base + i];
            float v = vals[base + i];
            int f = (int)(((unsigned long long)r * M) >> S);
            int lr = (int)r - f * d;
            int cs = f >> 4;
            cs8[k] = cs;
            rk8[k] = atomicAdd(&histC[cs], 1);
            pk8[k] = ((unsigned long long)__float_as_uint(v) << 32) |
                     ((unsigned)f << 20) | ((unsigned)lr << 13) | (unsigned)c;
        }
    }
    __syncthreads();
    if (t < 64) {
        int v = histC[t], x = v;
#pragma unroll
        for (int off = 1; off < 64; off <<= 1) {
            int y = __shfl_up(x, off, 64);
            if (t >= off) x += y;
        }
        scC[t] = x;
        if (v > 0) {
            int g = atomicAdd(&cursorC[t], v);
            adjC[t] = g - (x - v);
        }
    }
    __syncthreads();
#pragma unroll
    for (int k = 0; k < 8; ++k)
        if (cs8[k] >= 0) stage[(scC[cs8[k]] - histC[cs8[k]]) + rk8[k]] = pk8[k];
    __syncthreads();
    for (int i = t; i < count; i += 512) {
        unsigned long long p = stage[i];
        int cs = (int)((p >> 24) & 63);
        pairs1[adjC[cs] + i] = p;
    }
}

// Pass 2: re-bin coarse-sorted pairs to fine buckets (chunk sees ~16 fine ids
// -> runs ~2 KB). No coarse-boundary logic needed: fine id is in the pair.
__global__ __launch_bounds__(1024) void k_bin2(const unsigned long long* __restrict__ pairs1,
        int nnz, int* __restrict__ cursorF, unsigned long long* __restrict__ pairs2) {
    __shared__ unsigned long long stage[C2];  // 32 KB
    __shared__ int histF[NBF], scF[NBF], adjF[NBF];  // 12 KB
    __shared__ int wsum[16];
    int t = threadIdx.x, lane = t & 63, wv = t >> 6;
    long long base = (long long)blockIdx.x * C2;
    int count = (int)min((long long)C2, (long long)nnz - base);
    histF[t] = 0;
    __syncthreads();
    int f4[4], rk4[4];
    unsigned long long pk4[4];
#pragma unroll
    for (int k = 0; k < 4; ++k) {
        int i = t + (k << 10);
        f4[k] = -1;
        if (i < count) {
            unsigned long long p = pairs1[base + i];
            int f = (int)((p >> 20) & 1023);
            f4[k] = f;
            rk4[k] = atomicAdd(&histF[f], 1);
            pk4[k] = p;
        }
    }
    __syncthreads();
    int v = histF[t], x = v;
#pragma unroll
    for (int off = 1; off < 64; off <<= 1) {
        int y = __shfl_up(x, off, 64);
        if (lane >= off) x += y;
    }
    if (lane == 63) wsum[wv] = x;
    __syncthreads();
    if (t < 16) {
        int s = wsum[t], xs = s;
#pragma unroll
        for (int off = 1; off < 16; off <<= 1) {
            int y = __shfl_up(xs, off, 16);
            if (t >= off) xs += y;
        }
        wsum[t] = xs - s;
    }
    __syncthreads();
    int incl = x + wsum[wv];
    scF[t] = incl;
    if (v > 0) {
        int g = atomicAdd(&cursorF[t], v);
        adjF[t] = g - (incl - v);
    }
    __syncthreads();
#pragma unroll
    for (int k = 0; k < 4; ++k)
        if (f4[k] >= 0) stage[(scF[f4[k]] - histF[f4[k]]) + rk4[k]] = pk4[k];
    __syncthreads();
    for (int i = t; i < count; i += 1024) {
        unsigned long long p = stage[i];
        int f = (int)((p >> 20) & 1023);
        pairs2[adjF[f] + i] = p;
    }
}

// Fallback (small ws): direct source -> fine buckets (R4-style runs, correct).
__global__ __launch_bounds__(1024) void k_bin_direct(const int* __restrict__ rows,
        const int* __restrict__ cols, const float* __restrict__ vals, int nnz,
        unsigned M, int S, int d, int* __restrict__ cursorF,
        unsigned long long* __restrict__ pairs1) {
    __shared__ unsigned long long stage[C2];
    __shared__ int histF[NBF], scF[NBF], adjF[NBF];
    __shared__ int wsum[16];
    int t = threadIdx.x, lane = t & 63, wv = t >> 6;
    long long base = (long long)blockIdx.x * C2;
    int count = (int)min((long long)C2, (long long)nnz - base);
    histF[t] = 0;
    __syncthreads();
    int f4[4], rk4[4];
    unsigned long long pk4[4];
#pragma unroll
    for (int k = 0; k < 4; ++k) {
        int i = t + (k << 10);
        f4[k] = -1;
        if (i < count) {
            unsigned r = (unsigned)rows[base + i];
            int c = cols[base + i];
            float vv = vals[base + i];
            int f = (int)(((unsigned long long)r * M) >> S);
            int lr = (int)r - f * d;
            f4[k] = f;
            rk4[k] = atomicAdd(&histF[f], 1);
            pk4[k] = ((unsigned long long)__float_as_uint(vv) << 32) |
                     ((unsigned)f << 20) | ((unsigned)lr << 13) | (unsigned)c;
        }
    }
    __syncthreads();
    int v = histF[t], x = v;
#pragma unroll
    for (int off = 1; off < 64; off <<= 1) {
        int y = __shfl_up(x, off, 64);
        if (lane >= off) x += y;
    }
    if (lane == 63) wsum[wv] = x;
    __syncthreads();
    if (t < 16) {
        int s = wsum[t], xs = s;
#pragma unroll
        for (int off = 1; off < 16; off <<= 1) {
            int y = __shfl_up(xs, off, 16);
            if (t >= off) xs += y;
        }
        wsum[t] = xs - s;
    }
    __syncthreads();
    int incl = x + wsum[wv];
    scF[t] = incl;
    if (v > 0) {
        int g = atomicAdd(&cursorF[t], v);
        adjF[t] = g - (incl - v);
    }
    __syncthreads();
#pragma unroll
    for (int k = 0; k < 4; ++k)
        if (f4[k] >= 0) stage[(scF[f4[k]] - histF[f4[k]]) + rk4[k]] = pk4[k];
    __syncthreads();
    for (int i = t; i < count; i += 1024) {
        unsigned long long p = stage[i];
        int f = (int)((p >> 20) & 1023);
        pairs1[adjF[f] + i] = p;
    }
}

// Consumer: one block per fine bucket. Sort chunk by local row in LDS (int
// atomics + shfl scan), then 32 groups of 16 lanes each walk their own rows:
// group covers features via float4 (16 lanes x 16 B = full weight row; wave =
// 4 rows -> 1 KB coalesced weight load per instr). No float atomics.
__global__ __launch_bounds__(512) void k_spmm3(const unsigned long long* __restrict__ pairs,
        const int* __restrict__ fineBase, const float* __restrict__ weight,
        const float* __restrict__ bias, float* __restrict__ out, int d, int n) {
    __shared__ unsigned long long stage[CC];   // 16 KB
    __shared__ float acc[DMAX * 64];           // 32 KB
    __shared__ int histR[DMAX], scR[DMAX];     // 1 KB
    int b = blockIdx.x, t = threadIdx.x;
    int row0 = b * d;
    if (row0 >= n) return;
    int nrows = min(d, n - row0);
    int start = fineBase[b], end = fineBase[b + 1];

    for (int i = t; i < (nrows << 6); i += 512) acc[i] = 0.0f;

    int g = t >> 4, fq = t & 15;
    for (int cb = start; cb < end; cb += CC) {
        int cnt = min(CC, end - cb);
        if (t < DMAX) histR[t] = 0;
        __syncthreads();
        int lr4[4], rk4[4];
        unsigned long long pk4[4];
#pragma unroll
        for (int k = 0; k < 4; ++k) {
            int i = t + (k << 9);
            lr4[k] = -1;
            if (i < cnt) {
                unsigned long long p = pairs[cb + i];
                int lr = (int)((p >> 13) & 127);
                lr4[k] = lr;
                rk4[k] = atomicAdd(&histR[lr], 1);
                pk4[k] = p;
            }
        }
        __syncthreads();
        if (t < DMAX) {
            int v = histR[t], x = v;
            int lane = t & 63;
#pragma unroll
            for (int off = 1; off < 64; off <<= 1) {
                int y = __shfl_up(x, off, 64);
                if (lane >= off) x += y;
            }
            scR[t] = x;
        }
        __syncthreads();
        if (t >= 64 && t < DMAX) scR[t] += scR[63];
        __syncthreads();
#pragma unroll
        for (int k = 0; k < 4; ++k)
            if (lr4[k] >= 0) stage[(scR[lr4[k]] - histR[lr4[k]]) + rk4[k]] = pk4[k];
        __syncthreads();

        for (int r = g; r < nrows; r += 32) {
            int e = scR[r], s = e - histR[r];
            if (s >= e) continue;
            float4 a = {0.0f, 0.0f, 0.0f, 0.0f};
#pragma unroll 2
            for (int j = s; j < e; ++j) {
                unsigned long long p = stage[j];
                int c = (int)(p & 8191);
                float vv = __uint_as_float((unsigned)(p >> 32));
                const float4 w = *(const float4*)(weight + (c << 6) + (fq << 2));
                a.x = fmaf(vv, w.x, a.x);
                a.y = fmaf(vv, w.y, a.y);
                a.z = fmaf(vv, w.z, a.z);
                a.w = fmaf(vv, w.w, a.w);
            }
            float4* ap = (float4*)&acc[(r << 6) + (fq << 2)];
            float4 o = *ap;
            o.x += a.x; o.y += a.y; o.z += a.z; o.w += a.w;
            *ap = o;
        }
        __syncthreads();
    }

    for (int i = t; i < (nrows << 6); i += 512)
        out[((long long)row0 << 6) + i] = acc[i] + bias[i & 63];
}

extern "C" void kernel_launch(void* const* d_in, const int* in_sizes, int n_in,
                              void* d_out, int out_size, void* d_ws, size_t ws_size,
                              hipStream_t stream) {
    const int*   index  = (const int*)d_in[0];
    const float* value  = (const float*)d_in[1];
    const float* weight = (const float*)d_in[3];
    const float* bias   = (const float*)d_in[4];
    float*       out    = (float*)d_out;

    int nnz = in_sizes[0] / 2;
    int n   = out_size / 64;
    const int* rows = index;
    const int* cols = index + nnz;

    int d = (n + NBF - 1) / NBF;  // 98 for n=100000 (<= DMAX)
    unsigned M = 0;
    int S = 0;
    for (S = 20; S <= 40; ++S) {
        unsigned long long m = ((1ull << S) + (unsigned)d - 1) / (unsigned)d;
        unsigned long long e = m * (unsigned long long)d - (1ull << S);
        if (m <= 0xffffffffull && e * (unsigned long long)(n > 0 ? n - 1 : 0) < (1ull << S)) {
            M = (unsigned)m;
            break;
        }
    }

    char* ws = (char*)d_ws;
    int* gcnt     = (int*)ws;              // 4 KB
    int* fineBase = (int*)(ws + 8192);     // 1025 ints
    int* cursorF  = (int*)(ws + 16384);    // 1024 ints
    int* cursorC  = (int*)(ws + 20480);    // 64 ints
    size_t pairBytes = ((size_t)nnz * 8 + 255) & ~(size_t)255;
    unsigned long long* pairs1 = (unsigned long long*)(ws + 65536);
    unsigned long long* pairs2 = (unsigned long long*)(ws + 65536 + pairBytes);
    bool twoLevel = ws_size >= 65536 + 2 * pairBytes;

    k_zero1024<<<1, 1024, 0, stream>>>(gcnt);
    k_ghist<<<256, 512, 0, stream>>>(rows, nnz, M, S, gcnt);
    k_gscan<<<1, 1024, 0, stream>>>(gcnt, fineBase, cursorF, cursorC);

    int nChunks = (nnz + C1 - 1) / C1;
    const unsigned long long* pp;
    if (twoLevel) {
        k_bin1<<<nChunks, 512, 0, stream>>>(rows, cols, value, nnz, M, S, d, cursorC, pairs1);
        k_bin2<<<nChunks, 1024, 0, stream>>>(pairs1, nnz, cursorF, pairs2);
        pp = pairs2;
    } else {
        k_bin_direct<<<nChunks, 1024, 0, stream>>>(rows, cols, value, nnz, M, S, d, cursorF, pairs1);
        pp = pairs1;
    }
    k_spmm3<<<NBF, 512, 0, stream>>>(pp, fineBase, weight, bias, out, d, n);
}